// Round 8
// baseline (3731.173 us; speedup 1.0000x reference)
//
#include <hip/hip_runtime.h>

#define B 8
#define N 16384
#define S 2048
#define NS 32
#define CIN 16
#define NCELL 4096   // 16^3 morton cells

typedef float f32x2 __attribute__((ext_vector_type(2)));
typedef int   i32x2 __attribute__((ext_vector_type(2)));

// ---------------- DPP wave-64 reductions (all lanes active) ----------------
template<int CTRL>
__device__ __forceinline__ float dpp_fmax(float x) {
    int t = __builtin_amdgcn_update_dpp(0, __float_as_int(x), CTRL, 0xF, 0xF, true);
    return fmaxf(x, __int_as_float(t));
}
template<int CTRL>
__device__ __forceinline__ unsigned dpp_umax(unsigned x) {
    unsigned t = (unsigned)__builtin_amdgcn_update_dpp(0, (int)x, CTRL, 0xF, 0xF, true);
    return x > t ? x : t;
}
__device__ __forceinline__ float wave_fmax(float x) {
    x = dpp_fmax<0xB1>(x);      // quad_perm xor1
    x = dpp_fmax<0x4E>(x);      // quad_perm xor2
    x = dpp_fmax<0x114>(x);     // row_shr:4
    x = dpp_fmax<0x118>(x);     // row_shr:8
    x = dpp_fmax<0x142>(x);     // row_bcast:15
    x = dpp_fmax<0x143>(x);     // row_bcast:31
    return __int_as_float(__builtin_amdgcn_readlane(__float_as_int(x), 63));
}
__device__ __forceinline__ unsigned wave_umax(unsigned x) {
    x = dpp_umax<0xB1>(x);
    x = dpp_umax<0x4E>(x);
    x = dpp_umax<0x114>(x);
    x = dpp_umax<0x118>(x);
    x = dpp_umax<0x142>(x);
    x = dpp_umax<0x143>(x);
    return (unsigned)__builtin_amdgcn_readlane((int)x, 63);
}

__device__ __forceinline__ int expand4(int v) {
    // 4-bit -> every 3rd bit (12-bit morton component)
    return (v & 1) | ((v & 2) << 2) | ((v & 4) << 4) | ((v & 8) << 6);
}

// ---------------- bucket sort: 4096-cell morton order, SoA output ----------------
__global__ __launch_bounds__(1024) void bucket_kernel(const float* __restrict__ xyz,
                                                      float* __restrict__ Xp,
                                                      float* __restrict__ Yp,
                                                      float* __restrict__ Zp,
                                                      int* __restrict__ Ip) {
    const int b = blockIdx.x;
    const int t = threadIdx.x;
    const float* xb = xyz + (size_t)b * N * 3;

    __shared__ int hist[NCELL];          // 16KB (becomes base[] after scan)
    __shared__ int run[NCELL];           // 16KB
    __shared__ int pA[1024], pB[1024];   // 8KB
    for (int i = t; i < NCELL; i += 1024) { hist[i] = 0; run[i] = 0; }
    __syncthreads();

    int cell[16];
    float xs[16], ys[16], zs[16];
#pragma unroll
    for (int k = 0; k < 16; ++k) {
        const int n = t + (k << 10);
        const float x = xb[3 * n + 0];
        const float y = xb[3 * n + 1];
        const float z = xb[3 * n + 2];
        const int cx = min(15, max(0, (int)(x * 16.0f)));
        const int cy = min(15, max(0, (int)(y * 16.0f)));
        const int cz = min(15, max(0, (int)(z * 16.0f)));
        const int c = expand4(cx) | (expand4(cy) << 1) | (expand4(cz) << 2);
        cell[k] = c; xs[k] = x; ys[k] = y; zs[k] = z;
        atomicAdd(&hist[c], 1);
    }
    __syncthreads();

    // per-thread local scan of 4 cells, then block scan of 1024 partial sums
    const int h0 = hist[4 * t + 0], h1 = hist[4 * t + 1],
              h2 = hist[4 * t + 2], h3 = hist[4 * t + 3];
    const int lsum = h0 + h1 + h2 + h3;
    pA[t] = lsum;
    __syncthreads();
    int* cur = pA; int* nxt = pB;
    for (int off = 1; off < 1024; off <<= 1) {
        nxt[t] = cur[t] + ((t >= off) ? cur[t - off] : 0);
        __syncthreads();
        int* tmp = cur; cur = nxt; nxt = tmp;
    }
    const int excl = cur[t] - lsum;      // exclusive prefix of this thread's 4 cells
    __syncthreads();                     // all hist reads done -> safe to overwrite
    hist[4 * t + 0] = excl;
    hist[4 * t + 1] = excl + h0;
    hist[4 * t + 2] = excl + h0 + h1;
    hist[4 * t + 3] = excl + h0 + h1 + h2;
    __syncthreads();

#pragma unroll
    for (int k = 0; k < 16; ++k) {
        const int c = cell[k];
        const int pos = hist[c] + atomicAdd(&run[c], 1);
        const size_t o = (size_t)b * N + pos;
        Xp[o] = xs[k]; Yp[o] = ys[k]; Zp[o] = zs[k];
        Ip[o] = t + (k << 10);
    }
}

// ---------------- FPS: 512 thr x 32 pts, full VGPR residency, 4-slot atomic ----------------
__global__ __launch_bounds__(512) __attribute__((amdgpu_waves_per_eu(2, 2)))
void fps_prune_kernel(const float* __restrict__ xyz,
                      const float* __restrict__ Xp,
                      const float* __restrict__ Yp,
                      const float* __restrict__ Zp,
                      const int* __restrict__ Ip,
                      float* __restrict__ new_xyz) {
#pragma clang fp contract(off)
    const int b = blockIdx.x;
    const int t = threadIdx.x;           // 0..511
    const int lane = t & 63;
    const int w = t >> 6;                // 0..7
    const float* xb = xyz + (size_t)b * N * 3;
    const size_t base = (size_t)b * N + ((size_t)t << 5);   // 32 consecutive sorted pts

    f32x2 px[16], py[16], pz[16], md[16];
    i32x2 ip[16];
    {
        const f32x2* X2 = (const f32x2*)(Xp + base);
        const f32x2* Y2 = (const f32x2*)(Yp + base);
        const f32x2* Z2 = (const f32x2*)(Zp + base);
        const i32x2* I2 = (const i32x2*)(Ip + base);
#pragma unroll
        for (int j = 0; j < 16; ++j) {
            px[j] = X2[j]; py[j] = Y2[j]; pz[j] = Z2[j]; ip[j] = I2[j];
            md[j] = (f32x2){1e10f, 1e10f};
        }
    }

    // per-thread bbox (tight: points are Morton-adjacent)
    float lox = px[0].x, hix = px[0].x, loy = py[0].x, hiy = py[0].x,
          loz = pz[0].x, hiz = pz[0].x;
#pragma unroll
    for (int j = 0; j < 16; ++j) {
        lox = fminf(lox, fminf(px[j].x, px[j].y)); hix = fmaxf(hix, fmaxf(px[j].x, px[j].y));
        loy = fminf(loy, fminf(py[j].x, py[j].y)); hiy = fmaxf(hiy, fmaxf(py[j].x, py[j].y));
        loz = fminf(loz, fminf(pz[j].x, pz[j].y)); hiz = fmaxf(hiz, fmaxf(pz[j].x, pz[j].y));
    }

    __shared__ unsigned long long slot3[3][4];   // [phase][slot], depth-2 atomics
    if (t < 4) { slot3[0][t] = 0ull; slot3[1][t] = 0ull; slot3[2][t] = 0ull; }
    __syncthreads();

    int p = 0;
    float ub = 1e10f;
    int cand = ip[0].x;
    unsigned long long wkey = 0ull;
    float cx = xb[0], cy = xb[1], cz = xb[2];   // initial centroid = original point 0

    for (int it = 0; it < S; ++it) {
        if (t == 0) {
            float* o = new_xyz + ((size_t)b * S + it) * 3;
            o[0] = cx; o[1] = cy; o[2] = cz;
        }
        // exact conservative skip: lb*(1-2e-5) > ub  =>  d_fp32 > md for all 32 pts
        const float ddx = fmaxf(0.0f, fmaxf(lox - cx, cx - hix));
        const float ddy = fmaxf(0.0f, fmaxf(loy - cy, cy - hiy));
        const float ddz = fmaxf(0.0f, fmaxf(loz - cz, cz - hiz));
        const float lb = (ddx * ddx + ddy * ddy) + ddz * ddz;
        const bool upd = !(lb * 0.99998f > ub);

        if (__any(upd)) {                 // wave-uniform branch
            if (upd) {
                asm volatile("" : "+v"(px[0]), "+v"(px[1]), "+v"(px[2]), "+v"(px[3]),
                                  "+v"(px[4]), "+v"(px[5]), "+v"(px[6]), "+v"(px[7]));
                asm volatile("" : "+v"(px[8]), "+v"(px[9]), "+v"(px[10]), "+v"(px[11]),
                                  "+v"(px[12]), "+v"(px[13]), "+v"(px[14]), "+v"(px[15]));
                asm volatile("" : "+v"(py[0]), "+v"(py[1]), "+v"(py[2]), "+v"(py[3]),
                                  "+v"(py[4]), "+v"(py[5]), "+v"(py[6]), "+v"(py[7]));
                asm volatile("" : "+v"(py[8]), "+v"(py[9]), "+v"(py[10]), "+v"(py[11]),
                                  "+v"(py[12]), "+v"(py[13]), "+v"(py[14]), "+v"(py[15]));
                asm volatile("" : "+v"(pz[0]), "+v"(pz[1]), "+v"(pz[2]), "+v"(pz[3]),
                                  "+v"(pz[4]), "+v"(pz[5]), "+v"(pz[6]), "+v"(pz[7]));
                asm volatile("" : "+v"(pz[8]), "+v"(pz[9]), "+v"(pz[10]), "+v"(pz[11]),
                                  "+v"(pz[12]), "+v"(pz[13]), "+v"(pz[14]), "+v"(pz[15]));
                asm volatile("" : "+v"(ip[0]), "+v"(ip[1]), "+v"(ip[2]), "+v"(ip[3]),
                                  "+v"(ip[4]), "+v"(ip[5]), "+v"(ip[6]), "+v"(ip[7]));
                asm volatile("" : "+v"(ip[8]), "+v"(ip[9]), "+v"(ip[10]), "+v"(ip[11]),
                                  "+v"(ip[12]), "+v"(ip[13]), "+v"(ip[14]), "+v"(ip[15]));
                const f32x2 c2x = {cx, cx}, c2y = {cy, cy}, c2z = {cz, cz};
                f32x2 nu2 = {0.0f, 0.0f};
#pragma unroll
                for (int j = 0; j < 16; ++j) {
                    // identical rounding order to scalar version; v_pk_* ops
                    const f32x2 dx = px[j] - c2x;
                    const f32x2 dy = py[j] - c2y;
                    const f32x2 dz = pz[j] - c2z;
                    const f32x2 dd = (dx * dx + dy * dy) + dz * dz;
                    const f32x2 m = __builtin_elementwise_min(md[j], dd);
                    md[j] = m;
                    nu2 = __builtin_elementwise_max(nu2, m);
                }
                const float nu = fmaxf(nu2.x, nu2.y);   // max exact-assoc
                int c = 0x7fffffff;
#pragma unroll
                for (int j = 0; j < 16; ++j) {
                    if (md[j].x == nu) c = min(c, ip[j].x);
                    if (md[j].y == nu) c = min(c, ip[j].y);
                }
                ub = nu; cand = c;
            }
            // wave reduce (DPP): max ub, then min orig idx among ties
            const float wmax = wave_fmax(ub);
            unsigned cn = (ub == wmax) ? ~(unsigned)cand : 0u;
            cn = wave_umax(cn);
            wkey = ((unsigned long long)__float_as_uint(wmax) << 32)
                 | (unsigned long long)cn;
        }
        if (lane == 0) atomicMax(&slot3[p][w >> 1], wkey);   // depth-2 chains
        int pn = p + 1; if (pn == 3) pn = 0;
        if (t < 4) slot3[pn][t] = 0ull;   // reset for it+1 (readers done before bar it-1)
        __syncthreads();
        const unsigned long long s0 = slot3[p][0];
        const unsigned long long s1 = slot3[p][1];
        const unsigned long long s2 = slot3[p][2];
        const unsigned long long s3 = slot3[p][3];
        const unsigned long long m01 = s0 > s1 ? s0 : s1;
        const unsigned long long m23 = s2 > s3 ? s2 : s3;
        const unsigned long long r = m01 > m23 ? m01 : m23;
        // uniform index -> SGPR -> scalar loads, shortens dependent chain
        const int fu = __builtin_amdgcn_readfirstlane((int)(~(unsigned)r));
        cx = xb[3 * fu + 0];
        cy = xb[3 * fu + 1];
        cz = xb[3 * fu + 2];
        p = pn;
    }
}

// ---------------- fallback FPS (no workspace) ----------------
__global__ __launch_bounds__(1024) void fps_kernel(const float* __restrict__ xyz,
                                                   float* __restrict__ new_xyz) {
#pragma clang fp contract(off)
    const int b = blockIdx.x;
    const int t = threadIdx.x;
    const float* xb = xyz + (size_t)b * N * 3;

    float px[16], py[16], pz[16], md[16];
#pragma unroll
    for (int k = 0; k < 16; ++k) {
        const int n = t + (k << 10);
        px[k] = xb[3 * n + 0];
        py[k] = xb[3 * n + 1];
        pz[k] = xb[3 * n + 2];
        md[k] = 1e10f;
    }
    __shared__ float rv[2][16];
    __shared__ int slot[2];
    if (t == 0) { slot[0] = 0x7fffffff; slot[1] = 0x7fffffff; }
    __syncthreads();
    int far = 0, p = 0;
    const int lane = t & 63, w = t >> 6;
    for (int it = 0; it < S; ++it) {
        const float cx = xb[3 * far + 0], cy = xb[3 * far + 1], cz = xb[3 * far + 2];
        if (t == 0) {
            float* o = new_xyz + ((size_t)b * S + it) * 3;
            o[0] = cx; o[1] = cy; o[2] = cz;
        }
        float bestv = -1.0f;
#pragma unroll
        for (int k = 0; k < 16; ++k) {
            const float dx = __fsub_rn(px[k], cx);
            const float dy = __fsub_rn(py[k], cy);
            const float dz = __fsub_rn(pz[k], cz);
            const float d  = __fadd_rn(__fadd_rn(__fmul_rn(dx, dx), __fmul_rn(dy, dy)),
                                       __fmul_rn(dz, dz));
            const float m = fminf(md[k], d);
            md[k] = m;
            bestv = fmaxf(bestv, m);
        }
        float v = bestv;
#pragma unroll
        for (int off = 32; off >= 1; off >>= 1) v = fmaxf(v, __shfl_xor(v, off));
        if (lane == 0) rv[p][w] = v;
        __syncthreads();
        float u = rv[p][lane & 15];
#pragma unroll
        for (int off = 8; off >= 1; off >>= 1) u = fmaxf(u, __shfl_xor(u, off));
        if (t == 0) slot[p ^ 1] = 0x7fffffff;
        if (bestv == u) {
            int cnd2 = 0x7fffffff;
#pragma unroll
            for (int k = 0; k < 16; ++k)
                if (md[k] == u) cnd2 = min(cnd2, t + (k << 10));
            atomicMin(&slot[p], cnd2);
        }
        __syncthreads();
        far = slot[p];
        p ^= 1;
    }
}

// ---------------- ball query + group + MLP + maxpool: one wave per query ----------------
__global__ __launch_bounds__(64) void ball_mlp_kernel(
    const float* __restrict__ xyz,
    const float* __restrict__ feat,
    const float* __restrict__ W1, const float* __restrict__ b1,
    const float* __restrict__ W2, const float* __restrict__ b2,
    const float* __restrict__ W3, const float* __restrict__ b3,
    const float* __restrict__ new_xyz,
    float* __restrict__ out_feat) {
#pragma clang fp contract(off)
    const int q = blockIdx.x;          // b*S + s
    const int b = q >> 11;             // S = 2048
    const int lane = threadIdx.x;
    const float* xb = xyz + (size_t)b * N * 3;

    const double qx = (double)new_xyz[3 * q + 0];
    const double qy = (double)new_xyz[3 * q + 1];
    const double qz = (double)new_xyz[3 * q + 2];
    const double s2 = qx * qx + qy * qy + qz * qz;
    const double R2 = 0.1 * 0.1;

    __shared__ int idxbuf[NS];
    int found = 0;
    for (int bs = 0; bs < N; bs += 64) {
        const int n = bs + lane;
        const double x = (double)xb[3 * n + 0];
        const double y = (double)xb[3 * n + 1];
        const double z = (double)xb[3 * n + 2];
        const double n2 = x * x + y * y + z * z;
        const double dt = qx * x + qy * y + qz * z;
        const double d2 = (s2 + n2) - 2.0 * dt;
        const bool ok = (d2 <= R2);
        const unsigned long long msk = __ballot(ok);
        if (ok) {
            const int pos = found + (int)__popcll(msk & ((1ull << lane) - 1ull));
            if (pos < NS) idxbuf[pos] = n;
        }
        found += (int)__popcll(msk);
        if (found >= NS) break;
    }
    __syncthreads();
    if (lane == 0) {
        const int cnt = found < NS ? found : NS;
        const int first = (cnt > 0) ? idxbuf[0] : (N - 1);
        for (int j2 = cnt; j2 < NS; ++j2) idxbuf[j2] = first;
    }
    __syncthreads();

    const int j = lane & 31;           // neighbor
    const int h = lane >> 5;           // channel half
    const int nid = idxbuf[j];
    const float* fp = feat + ((size_t)b * N + nid) * CIN;
    float fv[CIN];
#pragma unroll
    for (int k = 0; k < CIN; ++k) fv[k] = fp[k];

    float h1[32];
#pragma unroll
    for (int c = 0; c < 32; ++c) {
        float a = b1[c];
#pragma unroll
        for (int k = 0; k < CIN; ++k) a = fmaf(fv[k], W1[(k << 5) + c], a);
        h1[c] = fmaxf(a, 0.0f);
    }
    float h2[32];
#pragma unroll
    for (int c = 0; c < 32; ++c) {
        float a = b2[c];
#pragma unroll
        for (int k = 0; k < 32; ++k) a = fmaf(h1[k], W2[(k << 5) + c], a);
        h2[c] = fmaxf(a, 0.0f);
    }
    const int cbase = h << 5;
    float mx[32];
#pragma unroll
    for (int c = 0; c < 32; ++c) {
        float a = b3[cbase + c];
#pragma unroll
        for (int k = 0; k < 32; ++k) a = fmaf(h2[k], W3[(k << 6) + cbase + c], a);
        mx[c] = a;
    }
#pragma unroll
    for (int off = 1; off <= 16; off <<= 1) {
#pragma unroll
        for (int c = 0; c < 32; ++c) mx[c] = fmaxf(mx[c], __shfl_xor(mx[c], off));
    }
    if (j == 0) {
        float* o = out_feat + (size_t)q * 64 + cbase;
#pragma unroll
        for (int c = 0; c < 32; ++c) o[c] = mx[c];
    }
}

extern "C" void kernel_launch(void* const* d_in, const int* in_sizes, int n_in,
                              void* d_out, int out_size, void* d_ws, size_t ws_size,
                              hipStream_t stream) {
    (void)in_sizes; (void)n_in; (void)out_size;
    const float* xyz  = (const float*)d_in[0];
    const float* feat = (const float*)d_in[1];
    const float* W1   = (const float*)d_in[2];
    const float* b1   = (const float*)d_in[3];
    const float* W2   = (const float*)d_in[4];
    const float* b2   = (const float*)d_in[5];
    const float* W3   = (const float*)d_in[6];
    const float* b3   = (const float*)d_in[7];

    float* out      = (float*)d_out;
    float* new_xyz  = out;                          // B*S*3 floats
    float* new_feat = out + (size_t)B * S * 3;      // B*S*64 floats

    const size_t need = (size_t)4 * B * N * sizeof(float);
    if (ws_size >= need) {
        float* Xp = (float*)d_ws;
        float* Yp = Xp + (size_t)B * N;
        float* Zp = Yp + (size_t)B * N;
        int*   Ip = (int*)(Zp + (size_t)B * N);
        bucket_kernel<<<B, 1024, 0, stream>>>(xyz, Xp, Yp, Zp, Ip);
        fps_prune_kernel<<<B, 512, 0, stream>>>(xyz, Xp, Yp, Zp, Ip, new_xyz);
    } else {
        fps_kernel<<<B, 1024, 0, stream>>>(xyz, new_xyz);
    }
    ball_mlp_kernel<<<B * S, 64, 0, stream>>>(xyz, feat, W1, b1, W2, b2, W3, b3,
                                              new_xyz, new_feat);
}

// Round 9
// 2877.062 us; speedup vs baseline: 1.2969x; 1.2969x over previous
//
#include <hip/hip_runtime.h>

#define B 8
#define N 16384
#define S 2048
#define NS 32
#define CIN 16
#define NCELL 4096   // 16^3 morton cells

typedef float f32x2 __attribute__((ext_vector_type(2)));
typedef int   i32x2 __attribute__((ext_vector_type(2)));
typedef unsigned long long u64;

// ---------------- DPP wave-64 reductions (all lanes active) ----------------
template<int CTRL>
__device__ __forceinline__ float dpp_fmax(float x) {
    int t = __builtin_amdgcn_update_dpp(0, __float_as_int(x), CTRL, 0xF, 0xF, true);
    return fmaxf(x, __int_as_float(t));
}
template<int CTRL>
__device__ __forceinline__ unsigned dpp_umax(unsigned x) {
    unsigned t = (unsigned)__builtin_amdgcn_update_dpp(0, (int)x, CTRL, 0xF, 0xF, true);
    return x > t ? x : t;
}
__device__ __forceinline__ float wave_fmax(float x) {
    x = dpp_fmax<0xB1>(x);      // quad_perm xor1
    x = dpp_fmax<0x4E>(x);      // quad_perm xor2
    x = dpp_fmax<0x114>(x);     // row_shr:4
    x = dpp_fmax<0x118>(x);     // row_shr:8
    x = dpp_fmax<0x142>(x);     // row_bcast:15
    x = dpp_fmax<0x143>(x);     // row_bcast:31
    return __int_as_float(__builtin_amdgcn_readlane(__float_as_int(x), 63));
}
__device__ __forceinline__ unsigned wave_umax(unsigned x) {
    x = dpp_umax<0xB1>(x);
    x = dpp_umax<0x4E>(x);
    x = dpp_umax<0x114>(x);
    x = dpp_umax<0x118>(x);
    x = dpp_umax<0x142>(x);
    x = dpp_umax<0x143>(x);
    return (unsigned)__builtin_amdgcn_readlane((int)x, 63);
}

__device__ __forceinline__ int expand4(int v) {
    // 4-bit -> every 3rd bit (12-bit morton component)
    return (v & 1) | ((v & 2) << 2) | ((v & 4) << 4) | ((v & 8) << 6);
}
__device__ __forceinline__ u64 u64max(u64 a, u64 b) { return a > b ? a : b; }

// ---------------- bucket sort: 4096-cell morton order, SoA output ----------------
__global__ __launch_bounds__(1024) void bucket_kernel(const float* __restrict__ xyz,
                                                      float* __restrict__ Xp,
                                                      float* __restrict__ Yp,
                                                      float* __restrict__ Zp,
                                                      int* __restrict__ Ip) {
    const int b = blockIdx.x;
    const int t = threadIdx.x;
    const float* xb = xyz + (size_t)b * N * 3;

    __shared__ int hist[NCELL];          // 16KB (becomes base[] after scan)
    __shared__ int run[NCELL];           // 16KB
    __shared__ int pA[1024], pB[1024];   // 8KB
    for (int i = t; i < NCELL; i += 1024) { hist[i] = 0; run[i] = 0; }
    __syncthreads();

    int cell[16];
    float xs[16], ys[16], zs[16];
#pragma unroll
    for (int k = 0; k < 16; ++k) {
        const int n = t + (k << 10);
        const float x = xb[3 * n + 0];
        const float y = xb[3 * n + 1];
        const float z = xb[3 * n + 2];
        const int cx = min(15, max(0, (int)(x * 16.0f)));
        const int cy = min(15, max(0, (int)(y * 16.0f)));
        const int cz = min(15, max(0, (int)(z * 16.0f)));
        const int c = expand4(cx) | (expand4(cy) << 1) | (expand4(cz) << 2);
        cell[k] = c; xs[k] = x; ys[k] = y; zs[k] = z;
        atomicAdd(&hist[c], 1);
    }
    __syncthreads();

    // per-thread local scan of 4 cells, then block scan of 1024 partial sums
    const int h0 = hist[4 * t + 0], h1 = hist[4 * t + 1],
              h2 = hist[4 * t + 2], h3 = hist[4 * t + 3];
    const int lsum = h0 + h1 + h2 + h3;
    pA[t] = lsum;
    __syncthreads();
    int* cur = pA; int* nxt = pB;
    for (int off = 1; off < 1024; off <<= 1) {
        nxt[t] = cur[t] + ((t >= off) ? cur[t - off] : 0);
        __syncthreads();
        int* tmp = cur; cur = nxt; nxt = tmp;
    }
    const int excl = cur[t] - lsum;      // exclusive prefix of this thread's 4 cells
    __syncthreads();                     // all hist reads done -> safe to overwrite
    hist[4 * t + 0] = excl;
    hist[4 * t + 1] = excl + h0;
    hist[4 * t + 2] = excl + h0 + h1;
    hist[4 * t + 3] = excl + h0 + h1 + h2;
    __syncthreads();

#pragma unroll
    for (int k = 0; k < 16; ++k) {
        const int c = cell[k];
        const int pos = hist[c] + atomicAdd(&run[c], 1);
        const size_t o = (size_t)b * N + pos;
        Xp[o] = xs[k]; Yp[o] = ys[k]; Zp[o] = zs[k];
        Ip[o] = t + (k << 10);
    }
}

// ---------------- FPS: bbox prune + packed update + slot/tree reduce + prefetch ----------------
__global__ __launch_bounds__(1024, 1) void fps_prune_kernel(const float* __restrict__ xyz,
                                                            const float* __restrict__ Xp,
                                                            const float* __restrict__ Yp,
                                                            const float* __restrict__ Zp,
                                                            const int* __restrict__ Ip,
                                                            float* __restrict__ new_xyz) {
#pragma clang fp contract(off)
    const int b = blockIdx.x;
    const int t = threadIdx.x;
    const int lane = t & 63;
    const int w = t >> 6;                // 0..15
    const float* xb = xyz + (size_t)b * N * 3;
    const size_t base = (size_t)b * N + ((size_t)t << 4);   // 16 consecutive sorted pts

    f32x2 px[8], py[8], pz[8], md[8];
    i32x2 ip[8];
    {
        const f32x2* X2 = (const f32x2*)(Xp + base);
        const f32x2* Y2 = (const f32x2*)(Yp + base);
        const f32x2* Z2 = (const f32x2*)(Zp + base);
        const i32x2* I2 = (const i32x2*)(Ip + base);
#pragma unroll
        for (int j = 0; j < 8; ++j) {
            px[j] = X2[j]; py[j] = Y2[j]; pz[j] = Z2[j]; ip[j] = I2[j];
            md[j] = (f32x2){1e10f, 1e10f};
        }
    }

    // per-thread bbox (tight: points are Morton-adjacent)
    float lox = px[0].x, hix = px[0].x, loy = py[0].x, hiy = py[0].x,
          loz = pz[0].x, hiz = pz[0].x;
#pragma unroll
    for (int j = 0; j < 8; ++j) {
        lox = fminf(lox, fminf(px[j].x, px[j].y)); hix = fmaxf(hix, fmaxf(px[j].x, px[j].y));
        loy = fminf(loy, fminf(py[j].x, py[j].y)); hiy = fmaxf(hiy, fmaxf(py[j].x, py[j].y));
        loz = fminf(loz, fminf(pz[j].x, pz[j].y)); hiz = fmaxf(hiz, fmaxf(pz[j].x, pz[j].y));
    }

    __shared__ u64 keyv[2][16];          // per-wave packed (val<<32 | ~orig_idx)
    int p = 0;

    float ub = 1e10f;
    int cand = ip[0].x;
    u64 wkey = 0ull;
    float cx = xb[0], cy = xb[1], cz = xb[2];   // initial centroid = original point 0

    for (int it = 0; it < S; ++it) {
        if (t == 0) {
            float* o = new_xyz + ((size_t)b * S + it) * 3;
            o[0] = cx; o[1] = cy; o[2] = cz;
        }
        // exact conservative skip: lb*(1-2e-5) > ub  =>  d_fp32 > md for all 16 pts
        const float ddx = fmaxf(0.0f, fmaxf(lox - cx, cx - hix));
        const float ddy = fmaxf(0.0f, fmaxf(loy - cy, cy - hiy));
        const float ddz = fmaxf(0.0f, fmaxf(loz - cz, cz - hiz));
        const float lb = (ddx * ddx + ddy * ddy) + ddz * ddz;
        const bool upd = !(lb * 0.99998f > ub);

        if (__any(upd)) {                 // wave-uniform branch
            if (upd) {
                asm volatile("" : "+v"(px[0]), "+v"(px[1]), "+v"(px[2]), "+v"(px[3]),
                                  "+v"(px[4]), "+v"(px[5]), "+v"(px[6]), "+v"(px[7]));
                asm volatile("" : "+v"(py[0]), "+v"(py[1]), "+v"(py[2]), "+v"(py[3]),
                                  "+v"(py[4]), "+v"(py[5]), "+v"(py[6]), "+v"(py[7]));
                asm volatile("" : "+v"(pz[0]), "+v"(pz[1]), "+v"(pz[2]), "+v"(pz[3]),
                                  "+v"(pz[4]), "+v"(pz[5]), "+v"(pz[6]), "+v"(pz[7]));
                asm volatile("" : "+v"(ip[0]), "+v"(ip[1]), "+v"(ip[2]), "+v"(ip[3]),
                                  "+v"(ip[4]), "+v"(ip[5]), "+v"(ip[6]), "+v"(ip[7]));
                const f32x2 c2x = {cx, cx}, c2y = {cy, cy}, c2z = {cz, cz};
                f32x2 nu2 = {0.0f, 0.0f};
#pragma unroll
                for (int j = 0; j < 8; ++j) {
                    // identical rounding order to scalar version; v_pk_* ops
                    const f32x2 dx = px[j] - c2x;
                    const f32x2 dy = py[j] - c2y;
                    const f32x2 dz = pz[j] - c2z;
                    const f32x2 dd = (dx * dx + dy * dy) + dz * dz;
                    const f32x2 m = __builtin_elementwise_min(md[j], dd);
                    md[j] = m;
                    nu2 = __builtin_elementwise_max(nu2, m);
                }
                const float nu = fmaxf(nu2.x, nu2.y);   // max exact-assoc
                int c = 0x7fffffff;
#pragma unroll
                for (int j = 0; j < 8; ++j) {
                    if (md[j].x == nu) c = min(c, ip[j].x);
                    if (md[j].y == nu) c = min(c, ip[j].y);
                }
                ub = nu; cand = c;
            }
            // wave reduce (DPP): max ub, then min orig idx among ties
            const float wmax = wave_fmax(ub);
            unsigned cn = (ub == wmax) ? ~(unsigned)cand : 0u;
            cn = wave_umax(cn);
            wkey = ((u64)__float_as_uint(wmax) << 32) | (u64)cn;
        }
        if (lane == 63) keyv[p][w] = wkey;     // plain write, no atomic, no reset

        // prefetch THIS wave's candidate centroid (block winner is one of the 16
        // candidates -> post-reduce load hits warmed cache). Issued pre-barrier,
        // consumed post-barrier so latency overlaps the barrier wait.
        const int sc = __builtin_amdgcn_readfirstlane(cand);
        const float pfx = xb[3 * sc + 0];
        const float pfy = xb[3 * sc + 1];
        const float pfz = xb[3 * sc + 2];

        __syncthreads();
        asm volatile("" :: "v"(pfx), "v"(pfy), "v"(pfz));

        // block reduce: 16 keys via broadcast LDS reads + u64 max tree
        const u64* kv = keyv[p];
        u64 k0 = u64max(kv[0],  kv[1]);
        u64 k1 = u64max(kv[2],  kv[3]);
        u64 k2 = u64max(kv[4],  kv[5]);
        u64 k3 = u64max(kv[6],  kv[7]);
        u64 k4 = u64max(kv[8],  kv[9]);
        u64 k5 = u64max(kv[10], kv[11]);
        u64 k6 = u64max(kv[12], kv[13]);
        u64 k7 = u64max(kv[14], kv[15]);
        k0 = u64max(k0, k1); k2 = u64max(k2, k3);
        k4 = u64max(k4, k5); k6 = u64max(k6, k7);
        k0 = u64max(k0, k2); k4 = u64max(k4, k6);
        const u64 rkey = u64max(k0, k4);

        const int fu = __builtin_amdgcn_readfirstlane((int)(~(unsigned)rkey));
        cx = xb[3 * fu + 0];
        cy = xb[3 * fu + 1];
        cz = xb[3 * fu + 2];
        p ^= 1;
    }
}

// ---------------- fallback FPS (no workspace) ----------------
__global__ __launch_bounds__(1024) void fps_kernel(const float* __restrict__ xyz,
                                                   float* __restrict__ new_xyz) {
#pragma clang fp contract(off)
    const int b = blockIdx.x;
    const int t = threadIdx.x;
    const float* xb = xyz + (size_t)b * N * 3;

    float px[16], py[16], pz[16], md[16];
#pragma unroll
    for (int k = 0; k < 16; ++k) {
        const int n = t + (k << 10);
        px[k] = xb[3 * n + 0];
        py[k] = xb[3 * n + 1];
        pz[k] = xb[3 * n + 2];
        md[k] = 1e10f;
    }
    __shared__ float rv[2][16];
    __shared__ int slot[2];
    if (t == 0) { slot[0] = 0x7fffffff; slot[1] = 0x7fffffff; }
    __syncthreads();
    int far = 0, p = 0;
    const int lane = t & 63, w = t >> 6;
    for (int it = 0; it < S; ++it) {
        const float cx = xb[3 * far + 0], cy = xb[3 * far + 1], cz = xb[3 * far + 2];
        if (t == 0) {
            float* o = new_xyz + ((size_t)b * S + it) * 3;
            o[0] = cx; o[1] = cy; o[2] = cz;
        }
        float bestv = -1.0f;
#pragma unroll
        for (int k = 0; k < 16; ++k) {
            const float dx = __fsub_rn(px[k], cx);
            const float dy = __fsub_rn(py[k], cy);
            const float dz = __fsub_rn(pz[k], cz);
            const float d  = __fadd_rn(__fadd_rn(__fmul_rn(dx, dx), __fmul_rn(dy, dy)),
                                       __fmul_rn(dz, dz));
            const float m = fminf(md[k], d);
            md[k] = m;
            bestv = fmaxf(bestv, m);
        }
        float v = bestv;
#pragma unroll
        for (int off = 32; off >= 1; off >>= 1) v = fmaxf(v, __shfl_xor(v, off));
        if (lane == 0) rv[p][w] = v;
        __syncthreads();
        float u = rv[p][lane & 15];
#pragma unroll
        for (int off = 8; off >= 1; off >>= 1) u = fmaxf(u, __shfl_xor(u, off));
        if (t == 0) slot[p ^ 1] = 0x7fffffff;
        if (bestv == u) {
            int cnd2 = 0x7fffffff;
#pragma unroll
            for (int k = 0; k < 16; ++k)
                if (md[k] == u) cnd2 = min(cnd2, t + (k << 10));
            atomicMin(&slot[p], cnd2);
        }
        __syncthreads();
        far = slot[p];
        p ^= 1;
    }
}

// ---------------- ball query + group + MLP + maxpool: one wave per query ----------------
__global__ __launch_bounds__(64) void ball_mlp_kernel(
    const float* __restrict__ xyz,
    const float* __restrict__ feat,
    const float* __restrict__ W1, const float* __restrict__ b1,
    const float* __restrict__ W2, const float* __restrict__ b2,
    const float* __restrict__ W3, const float* __restrict__ b3,
    const float* __restrict__ new_xyz,
    float* __restrict__ out_feat) {
#pragma clang fp contract(off)
    const int q = blockIdx.x;          // b*S + s
    const int b = q >> 11;             // S = 2048
    const int lane = threadIdx.x;
    const float* xb = xyz + (size_t)b * N * 3;

    const double qx = (double)new_xyz[3 * q + 0];
    const double qy = (double)new_xyz[3 * q + 1];
    const double qz = (double)new_xyz[3 * q + 2];
    const double s2 = qx * qx + qy * qy + qz * qz;
    const double R2 = 0.1 * 0.1;

    __shared__ int idxbuf[NS];
    int found = 0;
    for (int bs = 0; bs < N; bs += 64) {
        const int n = bs + lane;
        const double x = (double)xb[3 * n + 0];
        const double y = (double)xb[3 * n + 1];
        const double z = (double)xb[3 * n + 2];
        const double n2 = x * x + y * y + z * z;
        const double dt = qx * x + qy * y + qz * z;
        const double d2 = (s2 + n2) - 2.0 * dt;
        const bool ok = (d2 <= R2);
        const unsigned long long msk = __ballot(ok);
        if (ok) {
            const int pos = found + (int)__popcll(msk & ((1ull << lane) - 1ull));
            if (pos < NS) idxbuf[pos] = n;
        }
        found += (int)__popcll(msk);
        if (found >= NS) break;
    }
    __syncthreads();
    if (lane == 0) {
        const int cnt = found < NS ? found : NS;
        const int first = (cnt > 0) ? idxbuf[0] : (N - 1);
        for (int j2 = cnt; j2 < NS; ++j2) idxbuf[j2] = first;
    }
    __syncthreads();

    const int j = lane & 31;           // neighbor
    const int h = lane >> 5;           // channel half
    const int nid = idxbuf[j];
    const float* fp = feat + ((size_t)b * N + nid) * CIN;
    float fv[CIN];
#pragma unroll
    for (int k = 0; k < CIN; ++k) fv[k] = fp[k];

    float h1[32];
#pragma unroll
    for (int c = 0; c < 32; ++c) {
        float a = b1[c];
#pragma unroll
        for (int k = 0; k < CIN; ++k) a = fmaf(fv[k], W1[(k << 5) + c], a);
        h1[c] = fmaxf(a, 0.0f);
    }
    float h2[32];
#pragma unroll
    for (int c = 0; c < 32; ++c) {
        float a = b2[c];
#pragma unroll
        for (int k = 0; k < 32; ++k) a = fmaf(h1[k], W2[(k << 5) + c], a);
        h2[c] = fmaxf(a, 0.0f);
    }
    const int cbase = h << 5;
    float mx[32];
#pragma unroll
    for (int c = 0; c < 32; ++c) {
        float a = b3[cbase + c];
#pragma unroll
        for (int k = 0; k < 32; ++k) a = fmaf(h2[k], W3[(k << 6) + cbase + c], a);
        mx[c] = a;
    }
#pragma unroll
    for (int off = 1; off <= 16; off <<= 1) {
#pragma unroll
        for (int c = 0; c < 32; ++c) mx[c] = fmaxf(mx[c], __shfl_xor(mx[c], off));
    }
    if (j == 0) {
        float* o = out_feat + (size_t)q * 64 + cbase;
#pragma unroll
        for (int c = 0; c < 32; ++c) o[c] = mx[c];
    }
}

extern "C" void kernel_launch(void* const* d_in, const int* in_sizes, int n_in,
                              void* d_out, int out_size, void* d_ws, size_t ws_size,
                              hipStream_t stream) {
    (void)in_sizes; (void)n_in; (void)out_size;
    const float* xyz  = (const float*)d_in[0];
    const float* feat = (const float*)d_in[1];
    const float* W1   = (const float*)d_in[2];
    const float* b1   = (const float*)d_in[3];
    const float* W2   = (const float*)d_in[4];
    const float* b2   = (const float*)d_in[5];
    const float* W3   = (const float*)d_in[6];
    const float* b3   = (const float*)d_in[7];

    float* out      = (float*)d_out;
    float* new_xyz  = out;                          // B*S*3 floats
    float* new_feat = out + (size_t)B * S * 3;      // B*S*64 floats

    const size_t need = (size_t)4 * B * N * sizeof(float);
    if (ws_size >= need) {
        float* Xp = (float*)d_ws;
        float* Yp = Xp + (size_t)B * N;
        float* Zp = Yp + (size_t)B * N;
        int*   Ip = (int*)(Zp + (size_t)B * N);
        bucket_kernel<<<B, 1024, 0, stream>>>(xyz, Xp, Yp, Zp, Ip);
        fps_prune_kernel<<<B, 1024, 0, stream>>>(xyz, Xp, Yp, Zp, Ip, new_xyz);
    } else {
        fps_kernel<<<B, 1024, 0, stream>>>(xyz, new_xyz);
    }
    ball_mlp_kernel<<<B * S, 64, 0, stream>>>(xyz, feat, W1, b1, W2, b2, W3, b3,
                                              new_xyz, new_feat);
}

// Round 11
// 2437.021 us; speedup vs baseline: 1.5310x; 1.1806x over previous
//
#include <hip/hip_runtime.h>

#define B 8
#define N 16384
#define S 2048
#define NS 32
#define CIN 16
#define NCELL 4096   // 16^3 morton cells

typedef float f32x2 __attribute__((ext_vector_type(2)));
typedef int   i32x2 __attribute__((ext_vector_type(2)));
typedef unsigned long long u64;

// ---------------- DPP wave-64 reductions (all lanes active) ----------------
template<int CTRL>
__device__ __forceinline__ float dpp_fmax(float x) {
    int t = __builtin_amdgcn_update_dpp(0, __float_as_int(x), CTRL, 0xF, 0xF, true);
    return fmaxf(x, __int_as_float(t));
}
template<int CTRL>
__device__ __forceinline__ unsigned dpp_umax(unsigned x) {
    unsigned t = (unsigned)__builtin_amdgcn_update_dpp(0, (int)x, CTRL, 0xF, 0xF, true);
    return x > t ? x : t;
}
__device__ __forceinline__ float wave_fmax(float x) {
    x = dpp_fmax<0xB1>(x);      // quad_perm xor1
    x = dpp_fmax<0x4E>(x);      // quad_perm xor2
    x = dpp_fmax<0x114>(x);     // row_shr:4
    x = dpp_fmax<0x118>(x);     // row_shr:8
    x = dpp_fmax<0x142>(x);     // row_bcast:15
    x = dpp_fmax<0x143>(x);     // row_bcast:31
    return __int_as_float(__builtin_amdgcn_readlane(__float_as_int(x), 63));
}
__device__ __forceinline__ unsigned wave_umax(unsigned x) {
    x = dpp_umax<0xB1>(x);
    x = dpp_umax<0x4E>(x);
    x = dpp_umax<0x114>(x);
    x = dpp_umax<0x118>(x);
    x = dpp_umax<0x142>(x);
    x = dpp_umax<0x143>(x);
    return (unsigned)__builtin_amdgcn_readlane((int)x, 63);
}

__device__ __forceinline__ int expand4(int v) {
    // 4-bit -> every 3rd bit (12-bit morton component)
    return (v & 1) | ((v & 2) << 2) | ((v & 4) << 4) | ((v & 8) << 6);
}

// ---------------- bucket sort: 4096-cell morton order, SoA output ----------------
__global__ __launch_bounds__(1024) void bucket_kernel(const float* __restrict__ xyz,
                                                      float* __restrict__ Xp,
                                                      float* __restrict__ Yp,
                                                      float* __restrict__ Zp,
                                                      int* __restrict__ Ip) {
    const int b = blockIdx.x;
    const int t = threadIdx.x;
    const float* xb = xyz + (size_t)b * N * 3;

    __shared__ int hist[NCELL];          // 16KB (becomes base[] after scan)
    __shared__ int run[NCELL];           // 16KB
    __shared__ int pA[1024], pB[1024];   // 8KB
    for (int i = t; i < NCELL; i += 1024) { hist[i] = 0; run[i] = 0; }
    __syncthreads();

    int cell[16];
    float xs[16], ys[16], zs[16];
#pragma unroll
    for (int k = 0; k < 16; ++k) {
        const int n = t + (k << 10);
        const float x = xb[3 * n + 0];
        const float y = xb[3 * n + 1];
        const float z = xb[3 * n + 2];
        const int cx = min(15, max(0, (int)(x * 16.0f)));
        const int cy = min(15, max(0, (int)(y * 16.0f)));
        const int cz = min(15, max(0, (int)(z * 16.0f)));
        const int c = expand4(cx) | (expand4(cy) << 1) | (expand4(cz) << 2);
        cell[k] = c; xs[k] = x; ys[k] = y; zs[k] = z;
        atomicAdd(&hist[c], 1);
    }
    __syncthreads();

    // per-thread local scan of 4 cells, then block scan of 1024 partial sums
    const int h0 = hist[4 * t + 0], h1 = hist[4 * t + 1],
              h2 = hist[4 * t + 2], h3 = hist[4 * t + 3];
    const int lsum = h0 + h1 + h2 + h3;
    pA[t] = lsum;
    __syncthreads();
    int* cur = pA; int* nxt = pB;
    for (int off = 1; off < 1024; off <<= 1) {
        nxt[t] = cur[t] + ((t >= off) ? cur[t - off] : 0);
        __syncthreads();
        int* tmp = cur; cur = nxt; nxt = tmp;
    }
    const int excl = cur[t] - lsum;      // exclusive prefix of this thread's 4 cells
    __syncthreads();                     // all hist reads done -> safe to overwrite
    hist[4 * t + 0] = excl;
    hist[4 * t + 1] = excl + h0;
    hist[4 * t + 2] = excl + h0 + h1;
    hist[4 * t + 3] = excl + h0 + h1 + h2;
    __syncthreads();

#pragma unroll
    for (int k = 0; k < 16; ++k) {
        const int c = cell[k];
        const int pos = hist[c] + atomicAdd(&run[c], 1);
        const size_t o = (size_t)b * N + pos;
        Xp[o] = xs[k]; Yp[o] = ys[k]; Zp[o] = zs[k];
        Ip[o] = t + (k << 10);
    }
}

// ---------------- FPS: bbox prune + packed-f32 update + single-slot atomic reduce ----------------
// 4-phase slot rotation: reads of a phase's slot are separated from its next
// reset by TWO barriers (each with lgkmcnt(0) drain).
__global__ __launch_bounds__(1024, 1) void fps_prune_kernel(const float* __restrict__ xyz,
                                                            const float* __restrict__ Xp,
                                                            const float* __restrict__ Yp,
                                                            const float* __restrict__ Zp,
                                                            const int* __restrict__ Ip,
                                                            float* __restrict__ new_xyz) {
#pragma clang fp contract(off)
    const int b = blockIdx.x;
    const int t = threadIdx.x;
    const float* xb = xyz + (size_t)b * N * 3;
    const size_t base = (size_t)b * N + ((size_t)t << 4);   // 16 consecutive sorted pts

    f32x2 px[8], py[8], pz[8], md[8];
    i32x2 ip[8];
    {
        const f32x2* X2 = (const f32x2*)(Xp + base);
        const f32x2* Y2 = (const f32x2*)(Yp + base);
        const f32x2* Z2 = (const f32x2*)(Zp + base);
        const i32x2* I2 = (const i32x2*)(Ip + base);
#pragma unroll
        for (int j = 0; j < 8; ++j) {
            px[j] = X2[j]; py[j] = Y2[j]; pz[j] = Z2[j]; ip[j] = I2[j];
            md[j] = (f32x2){1e10f, 1e10f};
        }
    }

    // per-thread bbox (tight: points are Morton-adjacent)
    float lox = px[0].x, hix = px[0].x, loy = py[0].x, hiy = py[0].x,
          loz = pz[0].x, hiz = pz[0].x;
#pragma unroll
    for (int j = 0; j < 8; ++j) {
        lox = fminf(lox, fminf(px[j].x, px[j].y)); hix = fmaxf(hix, fmaxf(px[j].x, px[j].y));
        loy = fminf(loy, fminf(py[j].x, py[j].y)); hiy = fmaxf(hiy, fmaxf(py[j].x, py[j].y));
        loz = fminf(loz, fminf(pz[j].x, pz[j].y)); hiz = fmaxf(hiz, fmaxf(pz[j].x, pz[j].y));
    }

    __shared__ u64 slotp[4];             // [phase], 4-phase rotation
    if (t == 0) { slotp[0] = 0ull; slotp[1] = 0ull; slotp[2] = 0ull; slotp[3] = 0ull; }
    __syncthreads();

    int p = 0;
    float ub = 1e10f;
    int cand = ip[0].x;
    u64 wkey = 0ull;
    float cx = xb[0], cy = xb[1], cz = xb[2];   // initial centroid = original point 0

    for (int it = 0; it < S; ++it) {
        if (t == 0) {
            float* o = new_xyz + ((size_t)b * S + it) * 3;
            o[0] = cx; o[1] = cy; o[2] = cz;
        }
        // exact conservative skip: lb*(1-2e-5) > ub  =>  d_fp32 > md for all 16 pts
        const float ddx = fmaxf(0.0f, fmaxf(lox - cx, cx - hix));
        const float ddy = fmaxf(0.0f, fmaxf(loy - cy, cy - hiy));
        const float ddz = fmaxf(0.0f, fmaxf(loz - cz, cz - hiz));
        const float lb = (ddx * ddx + ddy * ddy) + ddz * ddz;
        const bool upd = !(lb * 0.99998f > ub);

        if (__any(upd)) {                 // wave-uniform branch
            if (upd) {
                asm volatile("" : "+v"(px[0]), "+v"(px[1]), "+v"(px[2]), "+v"(px[3]),
                                  "+v"(px[4]), "+v"(px[5]), "+v"(px[6]), "+v"(px[7]));
                asm volatile("" : "+v"(py[0]), "+v"(py[1]), "+v"(py[2]), "+v"(py[3]),
                                  "+v"(py[4]), "+v"(py[5]), "+v"(py[6]), "+v"(py[7]));
                asm volatile("" : "+v"(pz[0]), "+v"(pz[1]), "+v"(pz[2]), "+v"(pz[3]),
                                  "+v"(pz[4]), "+v"(pz[5]), "+v"(pz[6]), "+v"(pz[7]));
                asm volatile("" : "+v"(ip[0]), "+v"(ip[1]), "+v"(ip[2]), "+v"(ip[3]),
                                  "+v"(ip[4]), "+v"(ip[5]), "+v"(ip[6]), "+v"(ip[7]));
                const f32x2 c2x = {cx, cx}, c2y = {cy, cy}, c2z = {cz, cz};
                f32x2 nu2 = {0.0f, 0.0f};
#pragma unroll
                for (int j = 0; j < 8; ++j) {
                    // identical rounding order to scalar version; v_pk_* ops
                    const f32x2 dx = px[j] - c2x;
                    const f32x2 dy = py[j] - c2y;
                    const f32x2 dz = pz[j] - c2z;
                    const f32x2 dd = (dx * dx + dy * dy) + dz * dz;
                    const f32x2 m = __builtin_elementwise_min(md[j], dd);
                    md[j] = m;
                    nu2 = __builtin_elementwise_max(nu2, m);
                }
                const float nu = fmaxf(nu2.x, nu2.y);   // max exact-assoc
                int c = 0x7fffffff;
#pragma unroll
                for (int j = 0; j < 8; ++j) {
                    if (md[j].x == nu) c = min(c, ip[j].x);
                    if (md[j].y == nu) c = min(c, ip[j].y);
                }
                ub = nu; cand = c;
            }
            // wave reduce (DPP): max ub, then min orig idx among ties
            const float wmax = wave_fmax(ub);
            unsigned cn = (ub == wmax) ? ~(unsigned)cand : 0u;
            cn = wave_umax(cn);
            wkey = ((u64)__float_as_uint(wmax) << 32) | (u64)cn;
        }
        if ((t & 63) == 0) atomicMax(&slotp[p], wkey);
        const int pn = (p + 1) & 3;
        if (t == 0) slotp[pn] = 0ull;     // reset for it+1; its last readers (it-3)
                                          // are two barriers upstream
        __syncthreads();
        const u64 r = slotp[p];
        // uniform index -> SGPR -> scalar loads, shortens dependent chain
        const int fu = __builtin_amdgcn_readfirstlane((int)(~(unsigned)r));
        cx = xb[3 * fu + 0];
        cy = xb[3 * fu + 1];
        cz = xb[3 * fu + 2];
        p = pn;
    }
}

// ---------------- fallback FPS (no workspace) ----------------
__global__ __launch_bounds__(1024) void fps_kernel(const float* __restrict__ xyz,
                                                   float* __restrict__ new_xyz) {
#pragma clang fp contract(off)
    const int b = blockIdx.x;
    const int t = threadIdx.x;
    const float* xb = xyz + (size_t)b * N * 3;

    float px[16], py[16], pz[16], md[16];
#pragma unroll
    for (int k = 0; k < 16; ++k) {
        const int n = t + (k << 10);
        px[k] = xb[3 * n + 0];
        py[k] = xb[3 * n + 1];
        pz[k] = xb[3 * n + 2];
        md[k] = 1e10f;
    }
    __shared__ float rv[2][16];
    __shared__ int slot[2];
    if (t == 0) { slot[0] = 0x7fffffff; slot[1] = 0x7fffffff; }
    __syncthreads();
    int far = 0, p = 0;
    const int lane = t & 63, w = t >> 6;
    for (int it = 0; it < S; ++it) {
        const float cx = xb[3 * far + 0], cy = xb[3 * far + 1], cz = xb[3 * far + 2];
        if (t == 0) {
            float* o = new_xyz + ((size_t)b * S + it) * 3;
            o[0] = cx; o[1] = cy; o[2] = cz;
        }
        float bestv = -1.0f;
#pragma unroll
        for (int k = 0; k < 16; ++k) {
            const float dx = __fsub_rn(px[k], cx);
            const float dy = __fsub_rn(py[k], cy);
            const float dz = __fsub_rn(pz[k], cz);
            const float d  = __fadd_rn(__fadd_rn(__fmul_rn(dx, dx), __fmul_rn(dy, dy)),
                                       __fmul_rn(dz, dz));
            const float m = fminf(md[k], d);
            md[k] = m;
            bestv = fmaxf(bestv, m);
        }
        float v = bestv;
#pragma unroll
        for (int off = 32; off >= 1; off >>= 1) v = fmaxf(v, __shfl_xor(v, off));
        if (lane == 0) rv[p][w] = v;
        __syncthreads();
        float u = rv[p][lane & 15];
#pragma unroll
        for (int off = 8; off >= 1; off >>= 1) u = fmaxf(u, __shfl_xor(u, off));
        if (t == 0) slot[p ^ 1] = 0x7fffffff;
        if (bestv == u) {
            int cnd2 = 0x7fffffff;
#pragma unroll
            for (int k = 0; k < 16; ++k)
                if (md[k] == u) cnd2 = min(cnd2, t + (k << 10));
            atomicMin(&slot[p], cnd2);
        }
        __syncthreads();
        far = slot[p];
        p ^= 1;
    }
}

// ---------------- ball query + group + MLP + maxpool: one wave per query ----------------
__global__ __launch_bounds__(64) void ball_mlp_kernel(
    const float* __restrict__ xyz,
    const float* __restrict__ feat,
    const float* __restrict__ W1, const float* __restrict__ b1,
    const float* __restrict__ W2, const float* __restrict__ b2,
    const float* __restrict__ W3, const float* __restrict__ b3,
    const float* __restrict__ new_xyz,
    float* __restrict__ out_feat) {
#pragma clang fp contract(off)
    const int q = blockIdx.x;          // b*S + s
    const int b = q >> 11;             // S = 2048
    const int lane = threadIdx.x;
    const float* xb = xyz + (size_t)b * N * 3;

    const double qx = (double)new_xyz[3 * q + 0];
    const double qy = (double)new_xyz[3 * q + 1];
    const double qz = (double)new_xyz[3 * q + 2];
    const double s2 = qx * qx + qy * qy + qz * qz;
    const double R2 = 0.1 * 0.1;

    __shared__ int idxbuf[NS];
    int found = 0;
    for (int bs = 0; bs < N; bs += 64) {
        const int n = bs + lane;
        const double x = (double)xb[3 * n + 0];
        const double y = (double)xb[3 * n + 1];
        const double z = (double)xb[3 * n + 2];
        const double n2 = x * x + y * y + z * z;
        const double dt = qx * x + qy * y + qz * z;
        const double d2 = (s2 + n2) - 2.0 * dt;
        const bool ok = (d2 <= R2);
        const unsigned long long msk = __ballot(ok);
        if (ok) {
            const int pos = found + (int)__popcll(msk & ((1ull << lane) - 1ull));
            if (pos < NS) idxbuf[pos] = n;
        }
        found += (int)__popcll(msk);
        if (found >= NS) break;
    }
    __syncthreads();
    if (lane == 0) {
        const int cnt = found < NS ? found : NS;
        const int first = (cnt > 0) ? idxbuf[0] : (N - 1);
        for (int j2 = cnt; j2 < NS; ++j2) idxbuf[j2] = first;
    }
    __syncthreads();

    const int j = lane & 31;           // neighbor
    const int h = lane >> 5;           // channel half
    const int nid = idxbuf[j];
    const float* fp = feat + ((size_t)b * N + nid) * CIN;
    float fv[CIN];
#pragma unroll
    for (int k = 0; k < CIN; ++k) fv[k] = fp[k];

    float h1[32];
#pragma unroll
    for (int c = 0; c < 32; ++c) {
        float a = b1[c];
#pragma unroll
        for (int k = 0; k < CIN; ++k) a = fmaf(fv[k], W1[(k << 5) + c], a);
        h1[c] = fmaxf(a, 0.0f);
    }
    float h2[32];
#pragma unroll
    for (int c = 0; c < 32; ++c) {
        float a = b2[c];
#pragma unroll
        for (int k = 0; k < 32; ++k) a = fmaf(h1[k], W2[(k << 5) + c], a);
        h2[c] = fmaxf(a, 0.0f);
    }
    const int cbase = h << 5;
    float mx[32];
#pragma unroll
    for (int c = 0; c < 32; ++c) {
        float a = b3[cbase + c];
#pragma unroll
        for (int k = 0; k < 32; ++k) a = fmaf(h2[k], W3[(k << 6) + cbase + c], a);
        mx[c] = a;
    }
#pragma unroll
    for (int off = 1; off <= 16; off <<= 1) {
#pragma unroll
        for (int c = 0; c < 32; ++c) mx[c] = fmaxf(mx[c], __shfl_xor(mx[c], off));
    }
    if (j == 0) {
        float* o = out_feat + (size_t)q * 64 + cbase;
#pragma unroll
        for (int c = 0; c < 32; ++c) o[c] = mx[c];
    }
}

extern "C" void kernel_launch(void* const* d_in, const int* in_sizes, int n_in,
                              void* d_out, int out_size, void* d_ws, size_t ws_size,
                              hipStream_t stream) {
    (void)in_sizes; (void)n_in; (void)out_size;
    const float* xyz  = (const float*)d_in[0];
    const float* feat = (const float*)d_in[1];
    const float* W1   = (const float*)d_in[2];
    const float* b1   = (const float*)d_in[3];
    const float* W2   = (const float*)d_in[4];
    const float* b2   = (const float*)d_in[5];
    const float* W3   = (const float*)d_in[6];
    const float* b3   = (const float*)d_in[7];

    float* out      = (float*)d_out;
    float* new_xyz  = out;                          // B*S*3 floats
    float* new_feat = out + (size_t)B * S * 3;      // B*S*64 floats

    const size_t need = (size_t)4 * B * N * sizeof(float);
    if (ws_size >= need) {
        float* Xp = (float*)d_ws;
        float* Yp = Xp + (size_t)B * N;
        float* Zp = Yp + (size_t)B * N;
        int*   Ip = (int*)(Zp + (size_t)B * N);
        bucket_kernel<<<B, 1024, 0, stream>>>(xyz, Xp, Yp, Zp, Ip);
        fps_prune_kernel<<<B, 1024, 0, stream>>>(xyz, Xp, Yp, Zp, Ip, new_xyz);
    } else {
        fps_kernel<<<B, 1024, 0, stream>>>(xyz, new_xyz);
    }
    ball_mlp_kernel<<<B * S, 64, 0, stream>>>(xyz, feat, W1, b1, W2, b2, W3, b3,
                                              new_xyz, new_feat);
}

// Round 12
// 2253.484 us; speedup vs baseline: 1.6557x; 1.0814x over previous
//
#include <hip/hip_runtime.h>

#define B 8
#define N 16384
#define S 2048
#define NS 32
#define CIN 16
#define NCELL 4096   // 16^3 morton cells
#define CCAP 512     // ball-query candidate cap (expected ~68 for this data)

typedef float f32x2 __attribute__((ext_vector_type(2)));
typedef int   i32x2 __attribute__((ext_vector_type(2)));
typedef unsigned long long u64;

// ---------------- DPP wave-64 reductions (all lanes active) ----------------
template<int CTRL>
__device__ __forceinline__ float dpp_fmax(float x) {
    int t = __builtin_amdgcn_update_dpp(0, __float_as_int(x), CTRL, 0xF, 0xF, true);
    return fmaxf(x, __int_as_float(t));
}
template<int CTRL>
__device__ __forceinline__ unsigned dpp_umax(unsigned x) {
    unsigned t = (unsigned)__builtin_amdgcn_update_dpp(0, (int)x, CTRL, 0xF, 0xF, true);
    return x > t ? x : t;
}
__device__ __forceinline__ float wave_fmax(float x) {
    x = dpp_fmax<0xB1>(x);      // quad_perm xor1
    x = dpp_fmax<0x4E>(x);      // quad_perm xor2
    x = dpp_fmax<0x114>(x);     // row_shr:4
    x = dpp_fmax<0x118>(x);     // row_shr:8
    x = dpp_fmax<0x142>(x);     // row_bcast:15
    x = dpp_fmax<0x143>(x);     // row_bcast:31
    return __int_as_float(__builtin_amdgcn_readlane(__float_as_int(x), 63));
}
__device__ __forceinline__ unsigned wave_umax(unsigned x) {
    x = dpp_umax<0xB1>(x);
    x = dpp_umax<0x4E>(x);
    x = dpp_umax<0x114>(x);
    x = dpp_umax<0x118>(x);
    x = dpp_umax<0x142>(x);
    x = dpp_umax<0x143>(x);
    return (unsigned)__builtin_amdgcn_readlane((int)x, 63);
}

__device__ __forceinline__ int expand4(int v) {
    // 4-bit -> every 3rd bit (morton component; works for 3-bit too)
    return (v & 1) | ((v & 2) << 2) | ((v & 4) << 4) | ((v & 8) << 6);
}

// ---------------- bucket sort: 4096-cell morton order, SoA + cell starts ----------------
__global__ __launch_bounds__(1024) void bucket_kernel(const float* __restrict__ xyz,
                                                      float* __restrict__ Xp,
                                                      float* __restrict__ Yp,
                                                      float* __restrict__ Zp,
                                                      int* __restrict__ Ip,
                                                      int* __restrict__ starts) {
    const int b = blockIdx.x;
    const int t = threadIdx.x;
    const float* xb = xyz + (size_t)b * N * 3;
    int* st = starts + (size_t)b * (NCELL + 1);

    __shared__ int hist[NCELL];          // becomes exclusive base[] after scan
    __shared__ int run[NCELL];
    __shared__ int pA[1024], pB[1024];
    for (int i = t; i < NCELL; i += 1024) { hist[i] = 0; run[i] = 0; }
    __syncthreads();

    int cell[16];
    float xs[16], ys[16], zs[16];
#pragma unroll
    for (int k = 0; k < 16; ++k) {
        const int n = t + (k << 10);
        const float x = xb[3 * n + 0];
        const float y = xb[3 * n + 1];
        const float z = xb[3 * n + 2];
        const int cx = min(15, max(0, (int)(x * 16.0f)));
        const int cy = min(15, max(0, (int)(y * 16.0f)));
        const int cz = min(15, max(0, (int)(z * 16.0f)));
        const int c = expand4(cx) | (expand4(cy) << 1) | (expand4(cz) << 2);
        cell[k] = c; xs[k] = x; ys[k] = y; zs[k] = z;
        atomicAdd(&hist[c], 1);
    }
    __syncthreads();

    const int h0 = hist[4 * t + 0], h1 = hist[4 * t + 1],
              h2 = hist[4 * t + 2], h3 = hist[4 * t + 3];
    const int lsum = h0 + h1 + h2 + h3;
    pA[t] = lsum;
    __syncthreads();
    int* cur = pA; int* nxt = pB;
    for (int off = 1; off < 1024; off <<= 1) {
        nxt[t] = cur[t] + ((t >= off) ? cur[t - off] : 0);
        __syncthreads();
        int* tmp = cur; cur = nxt; nxt = tmp;
    }
    const int excl = cur[t] - lsum;
    __syncthreads();                     // all hist reads done -> safe to overwrite
    hist[4 * t + 0] = excl;
    hist[4 * t + 1] = excl + h0;
    hist[4 * t + 2] = excl + h0 + h1;
    hist[4 * t + 3] = excl + h0 + h1 + h2;
    __syncthreads();

    // export exclusive-prefix starts for the cell-based ball query
    for (int i = t; i < NCELL; i += 1024) st[i] = hist[i];
    if (t == 0) st[NCELL] = N;

#pragma unroll
    for (int k = 0; k < 16; ++k) {
        const int c = cell[k];
        const int pos = hist[c] + atomicAdd(&run[c], 1);
        const size_t o = (size_t)b * N + pos;
        Xp[o] = xs[k]; Yp[o] = ys[k]; Zp[o] = zs[k];
        Ip[o] = t + (k << 10);
    }
}

// ---------------- FPS: bbox prune + packed-f32 update + single-slot atomic reduce ----------------
// (verbatim from the passing R11 kernel; 4-phase slot rotation)
__global__ __launch_bounds__(1024, 1) void fps_prune_kernel(const float* __restrict__ xyz,
                                                            const float* __restrict__ Xp,
                                                            const float* __restrict__ Yp,
                                                            const float* __restrict__ Zp,
                                                            const int* __restrict__ Ip,
                                                            float* __restrict__ new_xyz) {
#pragma clang fp contract(off)
    const int b = blockIdx.x;
    const int t = threadIdx.x;
    const float* xb = xyz + (size_t)b * N * 3;
    const size_t base = (size_t)b * N + ((size_t)t << 4);

    f32x2 px[8], py[8], pz[8], md[8];
    i32x2 ip[8];
    {
        const f32x2* X2 = (const f32x2*)(Xp + base);
        const f32x2* Y2 = (const f32x2*)(Yp + base);
        const f32x2* Z2 = (const f32x2*)(Zp + base);
        const i32x2* I2 = (const i32x2*)(Ip + base);
#pragma unroll
        for (int j = 0; j < 8; ++j) {
            px[j] = X2[j]; py[j] = Y2[j]; pz[j] = Z2[j]; ip[j] = I2[j];
            md[j] = (f32x2){1e10f, 1e10f};
        }
    }

    float lox = px[0].x, hix = px[0].x, loy = py[0].x, hiy = py[0].x,
          loz = pz[0].x, hiz = pz[0].x;
#pragma unroll
    for (int j = 0; j < 8; ++j) {
        lox = fminf(lox, fminf(px[j].x, px[j].y)); hix = fmaxf(hix, fmaxf(px[j].x, px[j].y));
        loy = fminf(loy, fminf(py[j].x, py[j].y)); hiy = fmaxf(hiy, fmaxf(py[j].x, py[j].y));
        loz = fminf(loz, fminf(pz[j].x, pz[j].y)); hiz = fmaxf(hiz, fmaxf(pz[j].x, pz[j].y));
    }

    __shared__ u64 slotp[4];             // [phase], 4-phase rotation
    if (t == 0) { slotp[0] = 0ull; slotp[1] = 0ull; slotp[2] = 0ull; slotp[3] = 0ull; }
    __syncthreads();

    int p = 0;
    float ub = 1e10f;
    int cand = ip[0].x;
    u64 wkey = 0ull;
    float cx = xb[0], cy = xb[1], cz = xb[2];

    for (int it = 0; it < S; ++it) {
        if (t == 0) {
            float* o = new_xyz + ((size_t)b * S + it) * 3;
            o[0] = cx; o[1] = cy; o[2] = cz;
        }
        const float ddx = fmaxf(0.0f, fmaxf(lox - cx, cx - hix));
        const float ddy = fmaxf(0.0f, fmaxf(loy - cy, cy - hiy));
        const float ddz = fmaxf(0.0f, fmaxf(loz - cz, cz - hiz));
        const float lb = (ddx * ddx + ddy * ddy) + ddz * ddz;
        const bool upd = !(lb * 0.99998f > ub);

        if (__any(upd)) {
            if (upd) {
                asm volatile("" : "+v"(px[0]), "+v"(px[1]), "+v"(px[2]), "+v"(px[3]),
                                  "+v"(px[4]), "+v"(px[5]), "+v"(px[6]), "+v"(px[7]));
                asm volatile("" : "+v"(py[0]), "+v"(py[1]), "+v"(py[2]), "+v"(py[3]),
                                  "+v"(py[4]), "+v"(py[5]), "+v"(py[6]), "+v"(py[7]));
                asm volatile("" : "+v"(pz[0]), "+v"(pz[1]), "+v"(pz[2]), "+v"(pz[3]),
                                  "+v"(pz[4]), "+v"(pz[5]), "+v"(pz[6]), "+v"(pz[7]));
                asm volatile("" : "+v"(ip[0]), "+v"(ip[1]), "+v"(ip[2]), "+v"(ip[3]),
                                  "+v"(ip[4]), "+v"(ip[5]), "+v"(ip[6]), "+v"(ip[7]));
                const f32x2 c2x = {cx, cx}, c2y = {cy, cy}, c2z = {cz, cz};
                f32x2 nu2 = {0.0f, 0.0f};
#pragma unroll
                for (int j = 0; j < 8; ++j) {
                    const f32x2 dx = px[j] - c2x;
                    const f32x2 dy = py[j] - c2y;
                    const f32x2 dz = pz[j] - c2z;
                    const f32x2 dd = (dx * dx + dy * dy) + dz * dz;
                    const f32x2 m = __builtin_elementwise_min(md[j], dd);
                    md[j] = m;
                    nu2 = __builtin_elementwise_max(nu2, m);
                }
                const float nu = fmaxf(nu2.x, nu2.y);
                int c = 0x7fffffff;
#pragma unroll
                for (int j = 0; j < 8; ++j) {
                    if (md[j].x == nu) c = min(c, ip[j].x);
                    if (md[j].y == nu) c = min(c, ip[j].y);
                }
                ub = nu; cand = c;
            }
            const float wmax = wave_fmax(ub);
            unsigned cn = (ub == wmax) ? ~(unsigned)cand : 0u;
            cn = wave_umax(cn);
            wkey = ((u64)__float_as_uint(wmax) << 32) | (u64)cn;
        }
        if ((t & 63) == 0) atomicMax(&slotp[p], wkey);
        const int pn = (p + 1) & 3;
        if (t == 0) slotp[pn] = 0ull;
        __syncthreads();
        const u64 r = slotp[p];
        const int fu = __builtin_amdgcn_readfirstlane((int)(~(unsigned)r));
        cx = xb[3 * fu + 0];
        cy = xb[3 * fu + 1];
        cz = xb[3 * fu + 2];
        p = pn;
    }
}

// ---------------- fallback FPS (no workspace) ----------------
__global__ __launch_bounds__(1024) void fps_kernel(const float* __restrict__ xyz,
                                                   float* __restrict__ new_xyz) {
#pragma clang fp contract(off)
    const int b = blockIdx.x;
    const int t = threadIdx.x;
    const float* xb = xyz + (size_t)b * N * 3;

    float px[16], py[16], pz[16], md[16];
#pragma unroll
    for (int k = 0; k < 16; ++k) {
        const int n = t + (k << 10);
        px[k] = xb[3 * n + 0];
        py[k] = xb[3 * n + 1];
        pz[k] = xb[3 * n + 2];
        md[k] = 1e10f;
    }
    __shared__ float rv[2][16];
    __shared__ int slot[2];
    if (t == 0) { slot[0] = 0x7fffffff; slot[1] = 0x7fffffff; }
    __syncthreads();
    int far = 0, p = 0;
    const int lane = t & 63, w = t >> 6;
    for (int it = 0; it < S; ++it) {
        const float cx = xb[3 * far + 0], cy = xb[3 * far + 1], cz = xb[3 * far + 2];
        if (t == 0) {
            float* o = new_xyz + ((size_t)b * S + it) * 3;
            o[0] = cx; o[1] = cy; o[2] = cz;
        }
        float bestv = -1.0f;
#pragma unroll
        for (int k = 0; k < 16; ++k) {
            const float dx = __fsub_rn(px[k], cx);
            const float dy = __fsub_rn(py[k], cy);
            const float dz = __fsub_rn(pz[k], cz);
            const float d  = __fadd_rn(__fadd_rn(__fmul_rn(dx, dx), __fmul_rn(dy, dy)),
                                       __fmul_rn(dz, dz));
            const float m = fminf(md[k], d);
            md[k] = m;
            bestv = fmaxf(bestv, m);
        }
        float v = bestv;
#pragma unroll
        for (int off = 32; off >= 1; off >>= 1) v = fmaxf(v, __shfl_xor(v, off));
        if (lane == 0) rv[p][w] = v;
        __syncthreads();
        float u = rv[p][lane & 15];
#pragma unroll
        for (int off = 8; off >= 1; off >>= 1) u = fmaxf(u, __shfl_xor(u, off));
        if (t == 0) slot[p ^ 1] = 0x7fffffff;
        if (bestv == u) {
            int cnd2 = 0x7fffffff;
#pragma unroll
            for (int k = 0; k < 16; ++k)
                if (md[k] == u) cnd2 = min(cnd2, t + (k << 10));
            atomicMin(&slot[p], cnd2);
        }
        __syncthreads();
        far = slot[p];
        p ^= 1;
    }
}

// ---------------- shared MLP tail (neighbors in sel[NS]) ----------------
__device__ __forceinline__ void mlp_tail(const float* __restrict__ feat,
                                         const float* __restrict__ W1, const float* __restrict__ b1,
                                         const float* __restrict__ W2, const float* __restrict__ b2,
                                         const float* __restrict__ W3, const float* __restrict__ b3,
                                         const int* sel, int b, int q, int lane,
                                         float* __restrict__ out_feat) {
    const int j = lane & 31;           // neighbor
    const int h = lane >> 5;           // channel half
    const int nid = sel[j];
    const float* fp = feat + ((size_t)b * N + nid) * CIN;
    float fv[CIN];
#pragma unroll
    for (int k = 0; k < CIN; ++k) fv[k] = fp[k];

    float h1[32];
#pragma unroll
    for (int c = 0; c < 32; ++c) {
        float a = b1[c];
#pragma unroll
        for (int k = 0; k < CIN; ++k) a = fmaf(fv[k], W1[(k << 5) + c], a);
        h1[c] = fmaxf(a, 0.0f);
    }
    float h2[32];
#pragma unroll
    for (int c = 0; c < 32; ++c) {
        float a = b2[c];
#pragma unroll
        for (int k = 0; k < 32; ++k) a = fmaf(h1[k], W2[(k << 5) + c], a);
        h2[c] = fmaxf(a, 0.0f);
    }
    const int cbase = h << 5;
    float mx[32];
#pragma unroll
    for (int c = 0; c < 32; ++c) {
        float a = b3[cbase + c];
#pragma unroll
        for (int k = 0; k < 32; ++k) a = fmaf(h2[k], W3[(k << 6) + cbase + c], a);
        mx[c] = a;
    }
#pragma unroll
    for (int off = 1; off <= 16; off <<= 1) {
#pragma unroll
        for (int c = 0; c < 32; ++c) mx[c] = fmaxf(mx[c], __shfl_xor(mx[c], off));
    }
    if (j == 0) {
        float* o = out_feat + (size_t)q * 64 + cbase;
#pragma unroll
        for (int c = 0; c < 32; ++c) o[c] = mx[c];
    }
}

// ---------------- ball query via morton cells + MLP + maxpool: one wave/query ----------------
__global__ __launch_bounds__(64) void ball_mlp_cells_kernel(
    const float* __restrict__ feat,
    const float* __restrict__ W1, const float* __restrict__ b1,
    const float* __restrict__ W2, const float* __restrict__ b2,
    const float* __restrict__ W3, const float* __restrict__ b3,
    const float* __restrict__ new_xyz,
    const float* __restrict__ Xp, const float* __restrict__ Yp,
    const float* __restrict__ Zp, const int* __restrict__ Ip,
    const int* __restrict__ starts,
    float* __restrict__ out_feat) {
#pragma clang fp contract(off)
    const int q = blockIdx.x;          // b*S + s
    const int b = q >> 11;             // S = 2048
    const int lane = threadIdx.x;
    const size_t bn = (size_t)b * N;

    const double qx = (double)new_xyz[3 * q + 0];
    const double qy = (double)new_xyz[3 * q + 1];
    const double qz = (double)new_xyz[3 * q + 2];
    const double s2 = qx * qx + qy * qy + qz * qz;
    const double R2 = 0.1 * 0.1;       // same bits as the reference's 0.1*0.1

    // 8^3-cell box covering the ball (2e-5 slack >> all f32 cell-assignment rounding)
    const int axl = min(7, max(0, (int)floor((qx - 0.1 - 2e-5) * 8.0)));
    const int axh = min(7, max(0, (int)floor((qx + 0.1 + 2e-5) * 8.0)));
    const int ayl = min(7, max(0, (int)floor((qy - 0.1 - 2e-5) * 8.0)));
    const int ayh = min(7, max(0, (int)floor((qy + 0.1 + 2e-5) * 8.0)));
    const int azl = min(7, max(0, (int)floor((qz - 0.1 - 2e-5) * 8.0)));
    const int azh = min(7, max(0, (int)floor((qz + 0.1 + 2e-5) * 8.0)));
    const int nx = axh - axl + 1, ny = ayh - ayl + 1, nz = azh - azl + 1;
    const int ncell = nx * ny * nz;    // <= 27 typical (<= 64 hard bound)

    // lane-parallel fetch of all cell ranges (one vmcnt wait instead of ncell serial)
    int s_ = 0, e_ = 0;
    if (lane < ncell) {
        const int lx = lane % nx;
        const int rr = lane / nx;
        const int ly = rr % ny;
        const int lz = rr / ny;
        const int code8 = expand4(axl + lx) | (expand4(ayl + ly) << 1)
                        | (expand4(azl + lz) << 2);      // 8^3 cell = 8 contiguous 16^3 cells
        const int* stp = starts + (size_t)b * (NCELL + 1) + (code8 << 3);
        s_ = stp[0];
        e_ = stp[8];
    }

    __shared__ int cbuf[CCAP];
    int cnt = 0;
    for (int c = 0; c < ncell; ++c) {
        const int cs = __shfl(s_, c);
        const int ce = __shfl(e_, c);
        for (int ii = cs; ii < ce; ii += 64) {
            const int i = ii + lane;
            const bool act = i < ce;
            const int ig = act ? i : cs;             // safe dummy index
            const double x = (double)Xp[bn + ig];
            const double y = (double)Yp[bn + ig];
            const double z = (double)Zp[bn + ig];
            const double n2 = x * x + y * y + z * z;
            const double dt = qx * x + qy * y + qz * z;
            const double d2 = (s2 + n2) - 2.0 * dt;  // identical formula to prior kernel
            const bool ok = act && (d2 <= R2);
            const unsigned long long msk = __ballot(ok);
            if (ok) {
                const int pos = cnt + (int)__popcll(msk & ((1ull << lane) - 1ull));
                if (pos < CCAP) cbuf[pos] = Ip[bn + ig];
            }
            cnt += (int)__popcll(msk);
        }
    }
    if (cnt > CCAP) cnt = CCAP;
    __syncthreads();

    // select the 32 smallest original indices (set semantics; maxpool is order-free,
    // and the reference's padding = duplicates of the min qualifying index)
    __shared__ int sel[NS];
    int myc[8];
#pragma unroll
    for (int r = 0; r < 8; ++r) {
        const int idx = lane + (r << 6);
        myc[r] = (idx < cnt) ? cbuf[idx] : 0x7fffffff;
    }
    const int nsel = cnt < NS ? cnt : NS;
    if (cnt <= NS) {
        // all candidates selected, any order
#pragma unroll
        for (int r = 0; r < 8; ++r) {
            const int idx = lane + (r << 6);
            if (idx < cnt) sel[idx] = myc[r];
        }
    } else {
        for (int k = 0; k < NS; ++k) {
            int lm = myc[0];
#pragma unroll
            for (int r = 1; r < 8; ++r) lm = min(lm, myc[r]);
            const int wm = (int)~wave_umax(~(unsigned)lm);   // wave-min
            if (lane == 0) sel[k] = wm;
#pragma unroll
            for (int r = 0; r < 8; ++r) if (myc[r] == wm) myc[r] = 0x7fffffff;
        }
    }
    __syncthreads();
    if (lane == 0) {
        int first;
        if (nsel > 0) {
            first = sel[0];
            for (int k = 1; k < nsel; ++k) first = min(first, sel[k]);  // min qualifying idx
        } else {
            first = N - 1;   // ref OOB clip (unreachable: query point is its own neighbor)
        }
        for (int k = nsel; k < NS; ++k) sel[k] = first;
    }
    __syncthreads();

    mlp_tail(feat, W1, b1, W2, b2, W3, b3, sel, b, q, lane, out_feat);
}

// ---------------- fallback: full-scan ball query + MLP (no workspace) ----------------
__global__ __launch_bounds__(64) void ball_mlp_kernel(
    const float* __restrict__ xyz,
    const float* __restrict__ feat,
    const float* __restrict__ W1, const float* __restrict__ b1,
    const float* __restrict__ W2, const float* __restrict__ b2,
    const float* __restrict__ W3, const float* __restrict__ b3,
    const float* __restrict__ new_xyz,
    float* __restrict__ out_feat) {
#pragma clang fp contract(off)
    const int q = blockIdx.x;
    const int b = q >> 11;
    const int lane = threadIdx.x;
    const float* xb = xyz + (size_t)b * N * 3;

    const double qx = (double)new_xyz[3 * q + 0];
    const double qy = (double)new_xyz[3 * q + 1];
    const double qz = (double)new_xyz[3 * q + 2];
    const double s2 = qx * qx + qy * qy + qz * qz;
    const double R2 = 0.1 * 0.1;

    __shared__ int idxbuf[NS];
    int found = 0;
    for (int bs = 0; bs < N; bs += 64) {
        const int n = bs + lane;
        const double x = (double)xb[3 * n + 0];
        const double y = (double)xb[3 * n + 1];
        const double z = (double)xb[3 * n + 2];
        const double n2 = x * x + y * y + z * z;
        const double dt = qx * x + qy * y + qz * z;
        const double d2 = (s2 + n2) - 2.0 * dt;
        const bool ok = (d2 <= R2);
        const unsigned long long msk = __ballot(ok);
        if (ok) {
            const int pos = found + (int)__popcll(msk & ((1ull << lane) - 1ull));
            if (pos < NS) idxbuf[pos] = n;
        }
        found += (int)__popcll(msk);
        if (found >= NS) break;
    }
    __syncthreads();
    if (lane == 0) {
        const int cnt = found < NS ? found : NS;
        const int first = (cnt > 0) ? idxbuf[0] : (N - 1);
        for (int j2 = cnt; j2 < NS; ++j2) idxbuf[j2] = first;
    }
    __syncthreads();
    mlp_tail(feat, W1, b1, W2, b2, W3, b3, idxbuf, b, q, lane, out_feat);
}

extern "C" void kernel_launch(void* const* d_in, const int* in_sizes, int n_in,
                              void* d_out, int out_size, void* d_ws, size_t ws_size,
                              hipStream_t stream) {
    (void)in_sizes; (void)n_in; (void)out_size;
    const float* xyz  = (const float*)d_in[0];
    const float* feat = (const float*)d_in[1];
    const float* W1   = (const float*)d_in[2];
    const float* b1   = (const float*)d_in[3];
    const float* W2   = (const float*)d_in[4];
    const float* b2   = (const float*)d_in[5];
    const float* W3   = (const float*)d_in[6];
    const float* b3   = (const float*)d_in[7];

    float* out      = (float*)d_out;
    float* new_xyz  = out;                          // B*S*3 floats
    float* new_feat = out + (size_t)B * S * 3;      // B*S*64 floats

    const size_t need = (size_t)4 * B * N * sizeof(float)
                      + (size_t)B * (NCELL + 1) * sizeof(int);
    if (ws_size >= need) {
        float* Xp = (float*)d_ws;
        float* Yp = Xp + (size_t)B * N;
        float* Zp = Yp + (size_t)B * N;
        int*   Ip = (int*)(Zp + (size_t)B * N);
        int*   St = Ip + (size_t)B * N;
        bucket_kernel<<<B, 1024, 0, stream>>>(xyz, Xp, Yp, Zp, Ip, St);
        fps_prune_kernel<<<B, 1024, 0, stream>>>(xyz, Xp, Yp, Zp, Ip, new_xyz);
        ball_mlp_cells_kernel<<<B * S, 64, 0, stream>>>(feat, W1, b1, W2, b2, W3, b3,
                                                        new_xyz, Xp, Yp, Zp, Ip, St,
                                                        new_feat);
    } else {
        fps_kernel<<<B, 1024, 0, stream>>>(xyz, new_xyz);
        ball_mlp_kernel<<<B * S, 64, 0, stream>>>(xyz, feat, W1, b1, W2, b2, W3, b3,
                                                  new_xyz, new_feat);
    }
}